// Round 6
// baseline (25.461 us; speedup 1.0000x reference)
//
#include <hip/hip_runtime.h>

#define D_IN 64
#define D_OUT 64
#define NS 8
#define NK 12
#define NF 12                 // 8 basis + relu,tanh,sig,x
#define NBN 2048
#define KSPLIT 8              // d-chunks
#define DCH 8                 // d per chunk
#define KCH (DCH * NF)        // 96
#define BNT 64                // bn per tile
#define NT (NBN / BNT)        // 32 tiles
#define KAN_EPS 1e-8f

// split-K arrival counters; zero-init (.bss). The reducing block resets its
// counter to 0 before exiting, so the invariant holds for every graph replay.
__device__ int g_cnt[NT];

__device__ inline float rcp_(float a) { return __builtin_amdgcn_rcpf(a); }

// reference Cox-de Boor (fp32, rcp instead of IEEE div; tolerance is 8.75e-2)
__device__ inline void basis8(float xv, const float* __restrict__ t, float* __restrict__ B)
{
    float Bb[11];
    #pragma unroll
    for (int i = 0; i < 11; ++i) Bb[i] = (xv >= t[i] && xv < t[i + 1]) ? 1.f : 0.f;
    #pragma unroll
    for (int i = 0; i < 10; ++i)
        Bb[i] = (xv - t[i]) * rcp_(t[i + 1] - t[i] + KAN_EPS) * Bb[i]
              + (t[i + 2] - xv) * rcp_(t[i + 2] - t[i + 1] + KAN_EPS) * Bb[i + 1];
    #pragma unroll
    for (int i = 0; i < 9; ++i)
        Bb[i] = (xv - t[i]) * rcp_(t[i + 2] - t[i] + KAN_EPS) * Bb[i]
              + (t[i + 3] - xv) * rcp_(t[i + 3] - t[i + 1] + KAN_EPS) * Bb[i + 1];
    #pragma unroll
    for (int i = 0; i < 8; ++i)
        Bb[i] = (xv - t[i]) * rcp_(t[i + 3] - t[i] + KAN_EPS) * Bb[i]
              + (t[i + 4] - xv) * rcp_(t[i + 4] - t[i + 1] + KAN_EPS) * Bb[i + 1];
    #pragma unroll
    for (int i = 0; i < 8; ++i) B[i] = Bb[i];
}

// ONE kernel: grid (32 bn-tiles, 8 k-splits), block 512 = 8 waves.
// Phase 1: build LDS F-slice + W-chunk from raw inputs (self-contained).
// Phase 2: register-tile GEMM (8 o per thread).
// Phase 3: split-K partials + last-block reduction (device-scope fence/atomic).
__global__ __launch_bounds__(512)
void kan_fused(const float* __restrict__ x,      // (4,512,64)
               const float* __restrict__ cp,     // (64,64,8)
               const float* __restrict__ knots,  // (64,64,12)
               const float* __restrict__ aw,     // (64,64,4)
               float* __restrict__ partial,      // ws: [8][64][2048]
               float* __restrict__ out)          // (4,64,512)
{
    __shared__ float sF[KCH][BNT];     // 24 KB
    __shared__ float sW[KCH][D_OUT];   // 24 KB
    __shared__ int s_mism, s_last;

    const int bt   = blockIdx.x;               // 0..31
    const int ks   = blockIdx.y;               // 0..7
    const int tid  = threadIdx.x;
    const int lane = tid & 63;
    const int wv   = __builtin_amdgcn_readfirstlane(tid >> 6);   // 0..7
    const int d0   = ks * DCH;
    const int bn   = bt * BNT + lane;

    if (tid == 0) { s_mism = 0; }
    __syncthreads();

    // ---- phase 1a: F-slice; wave wv owns d = d0+wv, lane owns bn ----
    {
        const int d = d0 + wv;
        const float xv = x[bn * D_IN + d];
        float t[NK];
        #pragma unroll
        for (int j = 0; j < NK; ++j) t[j] = knots[d * NK + j];   // o=0 row, s_load
        float B[8];
        basis8(xv, t, B);
        #pragma unroll
        for (int s = 0; s < 8; ++s) sF[wv * NF + s][lane] = B[s];
        const float v = __expf(-xv);
        sF[wv * NF + 8][lane]  = fmaxf(xv, 0.f);           // relu
        sF[wv * NF + 9][lane]  = 2.f * rcp_(1.f + v * v) - 1.f;  // tanh
        sF[wv * NF + 10][lane] = rcp_(1.f + v);            // sigmoid
        sF[wv * NF + 11][lane] = xv;                       // identity
    }

    // ---- phase 1b: W-chunk + knot o-uniformity check ----
    {
        const int dg = tid >> 6;         // 0..7
        const int o  = lane;             // 0..63
        const int d  = d0 + dg;
        const int od = o * D_IN + d;
        const float4 c0 = *(const float4*)&cp[od * NS];
        const float4 c1 = *(const float4*)&cp[od * NS + 4];
        const float4 av = *(const float4*)&aw[od * 4];
        sW[dg * NF + 0][o] = c0.x;  sW[dg * NF + 1][o] = c0.y;
        sW[dg * NF + 2][o] = c0.z;  sW[dg * NF + 3][o] = c0.w;
        sW[dg * NF + 4][o] = c1.x;  sW[dg * NF + 5][o] = c1.y;
        sW[dg * NF + 6][o] = c1.z;  sW[dg * NF + 7][o] = c1.w;
        sW[dg * NF + 8][o]  = 0.1f * av.x;
        sW[dg * NF + 9][o]  = 0.1f * av.y;
        sW[dg * NF + 10][o] = 0.1f * av.z;
        sW[dg * NF + 11][o] = 0.1f * av.w;

        int m = 0;
        #pragma unroll
        for (int j = 0; j < NK; ++j)
            m |= (knots[od * NK + j] != knots[d * NK + j]) ? 1 : 0;
        if (m) atomicOr(&s_mism, 1);
    }
    __syncthreads();

    // ---- phase 2: GEMM; thread = (og = wv -> 8 o's, lane = bn) ----
    const int og8 = __builtin_amdgcn_readfirstlane(wv * 8);
    float acc[8] = {0.f, 0.f, 0.f, 0.f, 0.f, 0.f, 0.f, 0.f};

    if (s_mism == 0) {
        #pragma unroll 4
        for (int k = 0; k < KCH; ++k) {
            const float f   = sF[k][lane];                       // conflict-free
            const float4 wA = *(const float4*)&sW[k][og8];       // wave-uniform broadcast
            const float4 wB = *(const float4*)&sW[k][og8 + 4];
            acc[0] = fmaf(f, wA.x, acc[0]);  acc[1] = fmaf(f, wA.y, acc[1]);
            acc[2] = fmaf(f, wA.z, acc[2]);  acc[3] = fmaf(f, wA.w, acc[3]);
            acc[4] = fmaf(f, wB.x, acc[4]);  acc[5] = fmaf(f, wB.y, acc[5]);
            acc[6] = fmaf(f, wB.z, acc[6]);  acc[7] = fmaf(f, wB.w, acc[7]);
        }
    } else {
        // general fallback: knots differ across o -> direct per-(o,d) compute
        for (int dg = 0; dg < DCH; ++dg) {
            const int d = d0 + dg;
            const float xv = x[bn * D_IN + d];
            const float v  = __expf(-xv);
            const float Ra = rcp_(1.f + v * v), Rb = rcp_(1.f + v);
            const float fr = fmaxf(xv, 0.f), fth = 2.f * Ra - 1.f;
            for (int j = 0; j < 8; ++j) {
                const int o  = og8 + j;
                const int od = o * D_IN + d;
                float t2[NK];
                #pragma unroll
                for (int jj = 0; jj < NK; ++jj) t2[jj] = knots[od * NK + jj];
                float B[8];
                basis8(xv, t2, B);
                float sp = 0.f;
                #pragma unroll
                for (int s = 0; s < NS; ++s) sp += B[s] * cp[od * NS + s];
                sp += 0.1f * (aw[od * 4 + 0] * fr + aw[od * 4 + 1] * fth
                            + aw[od * 4 + 2] * Rb + aw[od * 4 + 3] * xv);
                acc[j] += sp;
            }
        }
    }

    // ---- phase 3: split-K handoff ----
    #pragma unroll
    for (int j = 0; j < 8; ++j)
        partial[(size_t)(ks * D_OUT + og8 + j) * NBN + bn] = acc[j];

    __syncthreads();   // barrier semantics drain vmcnt -> block's stores are in L2
    if (tid == 0) {
        __threadfence();                                   // release: L2 writeback (agent scope)
        s_last = (atomicAdd(&g_cnt[bt], 1) == KSPLIT - 1); // device-scope counter
    }
    __syncthreads();
    if (!s_last) return;

    // last-arriving block for this bn-tile: reduce in fixed ks order (deterministic)
    if (tid == 0) g_cnt[bt] = 0;       // restore invariant for next call/replay
    __threadfence();                   // acquire: invalidate L2 before reading partials
    #pragma unroll
    for (int j = 0; j < 8; ++j) {
        float s = 0.f;
        #pragma unroll
        for (int q = 0; q < KSPLIT; ++q)
            s += partial[(size_t)(q * D_OUT + og8 + j) * NBN + bn];
        const int b = bn >> 9;
        const int n = bn & 511;
        out[((b * D_OUT + og8 + j) << 9) | n] = s;
    }
}

extern "C" void kernel_launch(void* const* d_in, const int* in_sizes, int n_in,
                              void* d_out, int out_size, void* d_ws, size_t ws_size,
                              hipStream_t stream) {
    const float* x     = (const float*)d_in[0];  // (4,512,64)
    const float* cp    = (const float*)d_in[1];  // (64,64,8)
    const float* knots = (const float*)d_in[2];  // (64,64,12)
    const float* aw    = (const float*)d_in[3];  // (64,64,4)
    float* out     = (float*)d_out;              // (4,64,512)
    float* partial = (float*)d_ws;               // 4 MB

    dim3 grid(NT, KSPLIT);                       // (32, 8)
    kan_fused<<<grid, 512, 0, stream>>>(x, cp, knots, aw, partial, out);
}

// Round 7
// 24.665 us; speedup vs baseline: 1.0323x; 1.0323x over previous
//
#include <hip/hip_runtime.h>

#define D_IN 64
#define D_OUT 64
#define NS 8
#define NK 12
#define NF 12                 // 8 basis + relu,tanh,sig,x
#define NBN 2048
#define KSPLIT 8              // d-chunks
#define DCH 8                 // d per chunk
#define KCH (DCH * NF)        // 96
#define BNT 64                // bn per tile
#define NT (NBN / BNT)        // 32 tiles
#define KAN_EPS 1e-8f

// split-K arrival counters; zero-init (.bss). The reducing block resets its
// counter before exiting, so the invariant holds for every graph replay.
__device__ int g_cnt[NT];

__device__ inline float rcp_(float a) { return __builtin_amdgcn_rcpf(a); }

// reference Cox-de Boor (fp32, rcp instead of IEEE div; tolerance 8.75e-2)
__device__ inline void basis8(float xv, const float* __restrict__ t, float* __restrict__ B)
{
    float Bb[11];
    #pragma unroll
    for (int i = 0; i < 11; ++i) Bb[i] = (xv >= t[i] && xv < t[i + 1]) ? 1.f : 0.f;
    #pragma unroll
    for (int i = 0; i < 10; ++i)
        Bb[i] = (xv - t[i]) * rcp_(t[i + 1] - t[i] + KAN_EPS) * Bb[i]
              + (t[i + 2] - xv) * rcp_(t[i + 2] - t[i + 1] + KAN_EPS) * Bb[i + 1];
    #pragma unroll
    for (int i = 0; i < 9; ++i)
        Bb[i] = (xv - t[i]) * rcp_(t[i + 2] - t[i] + KAN_EPS) * Bb[i]
              + (t[i + 3] - xv) * rcp_(t[i + 3] - t[i + 1] + KAN_EPS) * Bb[i + 1];
    #pragma unroll
    for (int i = 0; i < 8; ++i)
        Bb[i] = (xv - t[i]) * rcp_(t[i + 3] - t[i] + KAN_EPS) * Bb[i]
              + (t[i + 4] - xv) * rcp_(t[i + 4] - t[i + 1] + KAN_EPS) * Bb[i + 1];
    #pragma unroll
    for (int i = 0; i < 8; ++i) B[i] = Bb[i];
}

// ONE kernel: grid (32 bn-tiles, 8 k-splits), block 256 = 4 waves.
// Phase 1: build LDS F-slice [96][64] + W-chunk [96][64] from raw inputs.
// Phase 2: 4o x 4bn register-tile GEMM (2 x ds_read_b128 per 16 FMA).
// Phase 3: split-K partials + last-block reduction (fence/atomic, proven R6).
__global__ __launch_bounds__(256)
void kan_fused(const float* __restrict__ x,      // (4,512,64)
               const float* __restrict__ cp,     // (64,64,8)
               const float* __restrict__ knots,  // (64,64,12)
               const float* __restrict__ aw,     // (64,64,4)
               float* __restrict__ partial,      // ws: [8][64][2048]
               float* __restrict__ out)          // (4,64,512)
{
    __shared__ float sF[KCH][BNT];     // 24 KB
    __shared__ float sW[KCH][D_OUT];   // 24 KB
    __shared__ int s_mism, s_last;

    const int bt  = blockIdx.x;                // 0..31
    const int ks  = blockIdx.y;                // 0..7
    const int tid = threadIdx.x;               // 0..255
    const int d0  = ks * DCH;

    if (tid == 0) s_mism = 0;
    __syncthreads();

    // ---- phase 1a: F-slice; 512 (dg,bn) pairs, 2 per thread ----
    #pragma unroll
    for (int rep = 0; rep < 2; ++rep) {
        const int p    = tid + rep * 256;      // 0..511
        const int dg   = p >> 6;               // 0..7
        const int lane = p & 63;
        const int d    = d0 + dg;
        const float xv = x[(bt * BNT + lane) * D_IN + d];
        float t[NK];
        #pragma unroll
        for (int j = 0; j < NK; ++j) t[j] = knots[d * NK + j];   // o=0 row
        float B[8];
        basis8(xv, t, B);
        #pragma unroll
        for (int s = 0; s < 8; ++s) sF[dg * NF + s][lane] = B[s];
        const float v = __expf(-xv);
        sF[dg * NF + 8][lane]  = fmaxf(xv, 0.f);                 // relu
        sF[dg * NF + 9][lane]  = 2.f * rcp_(1.f + v * v) - 1.f;  // tanh
        sF[dg * NF + 10][lane] = rcp_(1.f + v);                  // sigmoid
        sF[dg * NF + 11][lane] = xv;                             // identity
    }

    // ---- phase 1b: W-chunk + knot o-uniformity check ----
    #pragma unroll
    for (int rep = 0; rep < 2; ++rep) {
        const int q  = tid + rep * 256;        // 0..511
        const int o  = q & 63;
        const int dg = q >> 6;                 // 0..7
        const int d  = d0 + dg;
        const int od = o * D_IN + d;
        const float4 c0 = *(const float4*)&cp[od * NS];
        const float4 c1 = *(const float4*)&cp[od * NS + 4];
        const float4 av = *(const float4*)&aw[od * 4];
        sW[dg * NF + 0][o] = c0.x;  sW[dg * NF + 1][o] = c0.y;
        sW[dg * NF + 2][o] = c0.z;  sW[dg * NF + 3][o] = c0.w;
        sW[dg * NF + 4][o] = c1.x;  sW[dg * NF + 5][o] = c1.y;
        sW[dg * NF + 6][o] = c1.z;  sW[dg * NF + 7][o] = c1.w;
        sW[dg * NF + 8][o]  = 0.1f * av.x;
        sW[dg * NF + 9][o]  = 0.1f * av.y;
        sW[dg * NF + 10][o] = 0.1f * av.z;
        sW[dg * NF + 11][o] = 0.1f * av.w;

        int m = 0;
        #pragma unroll
        for (int j = 0; j < NK; ++j)
            m |= (knots[od * NK + j] != knots[d * NK + j]) ? 1 : 0;
        if (m) atomicOr(&s_mism, 1);
    }
    __syncthreads();

    // ---- phase 2: 4o x 4bn register-tile GEMM ----
    const int og4 = (tid >> 4) << 2;           // 0,4,..,60
    const int bnq = (tid & 15) << 2;           // 0,4,..,60
    float acc[4][4] = {};

    if (s_mism == 0) {
        #pragma unroll 8
        for (int k = 0; k < KCH; ++k) {
            const float4 f4 = *(const float4*)&sF[k][bnq];
            const float4 w4 = *(const float4*)&sW[k][og4];
            acc[0][0] = fmaf(w4.x, f4.x, acc[0][0]);
            acc[0][1] = fmaf(w4.x, f4.y, acc[0][1]);
            acc[0][2] = fmaf(w4.x, f4.z, acc[0][2]);
            acc[0][3] = fmaf(w4.x, f4.w, acc[0][3]);
            acc[1][0] = fmaf(w4.y, f4.x, acc[1][0]);
            acc[1][1] = fmaf(w4.y, f4.y, acc[1][1]);
            acc[1][2] = fmaf(w4.y, f4.z, acc[1][2]);
            acc[1][3] = fmaf(w4.y, f4.w, acc[1][3]);
            acc[2][0] = fmaf(w4.z, f4.x, acc[2][0]);
            acc[2][1] = fmaf(w4.z, f4.y, acc[2][1]);
            acc[2][2] = fmaf(w4.z, f4.z, acc[2][2]);
            acc[2][3] = fmaf(w4.z, f4.w, acc[2][3]);
            acc[3][0] = fmaf(w4.w, f4.x, acc[3][0]);
            acc[3][1] = fmaf(w4.w, f4.y, acc[3][1]);
            acc[3][2] = fmaf(w4.w, f4.z, acc[3][2]);
            acc[3][3] = fmaf(w4.w, f4.w, acc[3][3]);
        }
    } else {
        // general fallback: knots differ across o -> direct per-(o,d) compute
        for (int dg = 0; dg < DCH; ++dg) {
            const int d = d0 + dg;
            #pragma unroll
            for (int bi = 0; bi < 4; ++bi) {
                const float xv = x[(bt * BNT + bnq + bi) * D_IN + d];
                const float v  = __expf(-xv);
                const float Ra = rcp_(1.f + v * v), Rb = rcp_(1.f + v);
                const float fr = fmaxf(xv, 0.f), fth = 2.f * Ra - 1.f;
                for (int oi = 0; oi < 4; ++oi) {
                    const int od = (og4 + oi) * D_IN + d;
                    float t2[NK];
                    #pragma unroll
                    for (int jj = 0; jj < NK; ++jj) t2[jj] = knots[od * NK + jj];
                    float B[8];
                    basis8(xv, t2, B);
                    float sp = 0.f;
                    #pragma unroll
                    for (int s = 0; s < NS; ++s) sp += B[s] * cp[od * NS + s];
                    sp += 0.1f * (aw[od * 4 + 0] * fr + aw[od * 4 + 1] * fth
                                + aw[od * 4 + 2] * Rb + aw[od * 4 + 3] * xv);
                    acc[oi][bi] += sp;
                }
            }
        }
    }

    // ---- phase 3: split-K handoff ----
    const int bnbase = bt * BNT + bnq;
    #pragma unroll
    for (int j = 0; j < 4; ++j)
        *(float4*)&partial[(size_t)(ks * D_OUT + og4 + j) * NBN + bnbase] =
            make_float4(acc[j][0], acc[j][1], acc[j][2], acc[j][3]);

    __syncthreads();   // barrier semantics drain vmcnt -> block's stores visible in L2
    if (tid == 0) {
        __threadfence();                                   // release
        s_last = (atomicAdd(&g_cnt[bt], 1) == KSPLIT - 1); // device-scope counter
    }
    __syncthreads();
    if (!s_last) return;

    // last block for this bn-tile: reduce in fixed ks order (deterministic)
    if (tid == 0) g_cnt[bt] = 0;       // restore invariant for next replay
    __threadfence();                   // acquire
    #pragma unroll
    for (int j = 0; j < 4; ++j) {
        float4 s = make_float4(0.f, 0.f, 0.f, 0.f);
        #pragma unroll
        for (int q = 0; q < KSPLIT; ++q) {
            const float4 p = *(const float4*)&partial[(size_t)(q * D_OUT + og4 + j) * NBN + bnbase];
            s.x += p.x; s.y += p.y; s.z += p.z; s.w += p.w;
        }
        const int b = bnbase >> 9;
        const int n = bnbase & 511;
        *(float4*)&out[((b * D_OUT + og4 + j) << 9) + n] = s;
    }
}

extern "C" void kernel_launch(void* const* d_in, const int* in_sizes, int n_in,
                              void* d_out, int out_size, void* d_ws, size_t ws_size,
                              hipStream_t stream) {
    const float* x     = (const float*)d_in[0];  // (4,512,64)
    const float* cp    = (const float*)d_in[1];  // (64,64,8)
    const float* knots = (const float*)d_in[2];  // (64,64,12)
    const float* aw    = (const float*)d_in[3];  // (64,64,4)
    float* out     = (float*)d_out;              // (4,64,512)
    float* partial = (float*)d_ws;               // 4 MB

    dim3 grid(NT, KSPLIT);                       // (32, 8)
    kan_fused<<<grid, 256, 0, stream>>>(x, cp, knots, aw, partial, out);
}